// Round 10
// baseline (549.256 us; speedup 1.0000x reference)
//
#include <hip/hip_runtime.h>

#define HH 12
#define SS 1024
#define CC 768
#define DD 64
#define NB 8

typedef _Float16 half8 __attribute__((ext_vector_type(8)));
typedef _Float16 half4 __attribute__((ext_vector_type(4)));
typedef float f32x4 __attribute__((ext_vector_type(4)));

// ---------------- f32 -> f16 convert (n4 = count/4) ----------------
__global__ __launch_bounds__(256) void cvt_f16(const float* __restrict__ src,
                                               _Float16* __restrict__ dst, int n4) {
  int i = blockIdx.x * 256 + threadIdx.x;
  int stride = gridDim.x * 256;
  for (; i < n4; i += stride) {
    f32x4 v = *reinterpret_cast<const f32x4*>(src + (size_t)i * 4);
    half4 o;
    o[0] = (_Float16)v[0]; o[1] = (_Float16)v[1];
    o[2] = (_Float16)v[2]; o[3] = (_Float16)v[3];
    *reinterpret_cast<half4*>(dst + (size_t)i * 4) = o;
  }
}

// ---------------- combine k-split halves + convert to f16 ----------------
__global__ __launch_bounds__(256) void combine_cvt(const float* __restrict__ A,
                                                   const float* __restrict__ B,
                                                   _Float16* __restrict__ dst, int n4) {
  int i = blockIdx.x * 256 + threadIdx.x;
  int stride = gridDim.x * 256;
  for (; i < n4; i += stride) {
    f32x4 a = *reinterpret_cast<const f32x4*>(A + (size_t)i * 4);
    f32x4 b = *reinterpret_cast<const f32x4*>(B + (size_t)i * 4);
    f32x4 s = a + b;
    half4 o;
    o[0] = (_Float16)s[0]; o[1] = (_Float16)s[1];
    o[2] = (_Float16)s[2]; o[3] = (_Float16)s[3];
    *reinterpret_cast<half4*>(dst + (size_t)i * 4) = o;
  }
}

// ---------------- transpose RxC f32 -> CxR f16 ----------------
__global__ __launch_bounds__(256) void transp_f16(const float* __restrict__ src,
                                                  _Float16* __restrict__ dst, int R, int C) {
  __shared__ float tile[32][33];
  int tx = threadIdx.x & 31, ty = threadIdx.x >> 5;  // 32 x 8
  int r0 = blockIdx.y * 32, c0 = blockIdx.x * 32;
#pragma unroll
  for (int i = 0; i < 4; i++)
    tile[ty + i * 8][tx] = src[(size_t)(r0 + ty + i * 8) * C + c0 + tx];
  __syncthreads();
#pragma unroll
  for (int i = 0; i < 4; i++)
    dst[(size_t)(c0 + ty + i * 8) * R + r0 + tx] = (_Float16)tile[tx][ty + i * 8];
}

// ---------------- generic B-transposed GEMM ----------------
// CMODE: 1 = f16 QK layout [((b*12+h)*1024+s)*64+d]; 2 = f16 VT layout [((b*12+h)*64+d)*1024+s];
//        3 = f32 C at [row*ldc+col]
template <int BM, int BN, int BK, int CMODE>
__global__ __launch_bounds__(256) void gemm_bt(
    const _Float16* __restrict__ Abase, const _Float16* __restrict__ Bbase,
    void* __restrict__ Cbase, int M, int N, int K, int lda, int ldb, int ldc,
    float scale) {
  constexpr int WTM = BM / 2, WTN = BN / 2;
  constexpr int FM = WTM / 16, FN = WTN / 16;
  constexpr int AP = BM * BK / (256 * 8), BP = BN * BK / (256 * 8);
  __shared__ _Float16 sA[BM * BK];
  __shared__ _Float16 sB[BN * BK];
  const int tid = threadIdx.x;
  const int lane = tid & 63, wid = tid >> 6;
  const int wr = wid >> 1, wc = wid & 1;
  const int l15 = lane & 15, lhi = lane >> 4;
  const _Float16* A = Abase;
  const _Float16* B = Bbase;
  const int m0 = blockIdx.y * BM, n0 = blockIdx.x * BN;

  f32x4 acc[FM][FN] = {};
  const int nkt = K / BK;
  for (int kt = 0; kt < nkt; ++kt) {
    half8 ar[AP], br[BP];
#pragma unroll
    for (int p = 0; p < AP; p++) {
      int e = (p * 256 + tid) * 8;
      int r = e / BK, c = e % BK;
      ar[p] = *reinterpret_cast<const half8*>(A + (long)(m0 + r) * lda + kt * BK + c);
    }
#pragma unroll
    for (int p = 0; p < BP; p++) {
      int e = (p * 256 + tid) * 8;
      int r = e / BK, c = e % BK;
      br[p] = *reinterpret_cast<const half8*>(B + (long)(n0 + r) * ldb + kt * BK + c);
    }
    __syncthreads();
#pragma unroll
    for (int p = 0; p < AP; p++) {
      int e = (p * 256 + tid) * 8;
      *reinterpret_cast<half8*>(&sA[e]) = ar[p];
    }
#pragma unroll
    for (int p = 0; p < BP; p++) {
      int e = (p * 256 + tid) * 8;
      *reinterpret_cast<half8*>(&sB[e]) = br[p];
    }
    __syncthreads();
#pragma unroll
    for (int ks = 0; ks < BK / 32; ++ks) {
      half8 af[FM], bf[FN];
#pragma unroll
      for (int fm = 0; fm < FM; fm++)
        af[fm] = *reinterpret_cast<const half8*>(
            &sA[(wr * WTM + fm * 16 + l15) * BK + ks * 32 + lhi * 8]);
#pragma unroll
      for (int fn = 0; fn < FN; fn++)
        bf[fn] = *reinterpret_cast<const half8*>(
            &sB[(wc * WTN + fn * 16 + l15) * BK + ks * 32 + lhi * 8]);
#pragma unroll
      for (int fm = 0; fm < FM; fm++)
#pragma unroll
        for (int fn = 0; fn < FN; fn++)
          acc[fm][fn] =
              __builtin_amdgcn_mfma_f32_16x16x32_f16(af[fm], bf[fn], acc[fm][fn], 0, 0, 0);
    }
  }

#pragma unroll
  for (int fm = 0; fm < FM; fm++) {
#pragma unroll
    for (int fn = 0; fn < FN; fn++) {
#pragma unroll
      for (int j = 0; j < 4; j++) {
        int row = m0 + wr * WTM + fm * 16 + lhi * 4 + j;
        int col = n0 + wc * WTN + fn * 16 + l15;
        float v = acc[fm][fn][j] * scale;
        if constexpr (CMODE == 1) {
          int b = row >> 10, s = row & 1023, h = col >> 6, d = col & 63;
          reinterpret_cast<_Float16*>(Cbase)[((long)(b * HH + h) * SS + s) * DD + d] =
              (_Float16)v;
        } else if constexpr (CMODE == 2) {
          int b = row >> 10, s = row & 1023, h = col >> 6, d = col & 63;
          reinterpret_cast<_Float16*>(Cbase)[((long)(b * HH + h) * DD + d) * SS + s] =
              (_Float16)v;
        } else {
          reinterpret_cast<float*>(Cbase)[(long)row * ldc + col] = v;
        }
      }
    }
  }
}

// Q tile in LDS, XOR-swizzled (T2): elem = (h*16+q)*64 + (col8 ^ (q&7))*8 + within.
// Rows stay 16B-aligned (real ds_read_b128), banks spread by row.

// ================= fused attention, pass 1: softmax denominators =================
// Grid (kchunk=4 x qtile=64 x b=8), 256 threads = 4 waves. Incremental premix.
__global__ __launch_bounds__(256, 1) void attn_sums(const _Float16* __restrict__ Qh,
                                                    const _Float16* __restrict__ Kh,
                                                    const float* __restrict__ Wpre,
                                                    float* __restrict__ S) {
  __shared__ _Float16 Qs[12 * 16 * 64];
  __shared__ float sW[144];  // Wpre row-major [h][i]
  __shared__ float sRed[4][12][16];
  const int tid = threadIdx.x, lane = tid & 63, wid = tid >> 6;
  const int l15 = lane & 15, g = lane >> 4;
  const int s7 = l15 & 7;
  const int b = blockIdx.z, q0 = blockIdx.y * 16, k0 = blockIdx.x * 256;

  for (int u = tid; u < 144; u += 256) sW[u] = Wpre[u];
  for (int u = tid; u < 12 * 16 * 8; u += 256) {
    int h = u >> 7, q = (u >> 3) & 15, e8 = u & 7;
    half8 v = *reinterpret_cast<const half8*>(
        Qh + ((size_t)(b * HH + h) * SS + q0 + q) * DD + e8 * 8);
    *reinterpret_cast<half8*>(&Qs[(h * 16 + q) * 64 + (e8 ^ (q & 7)) * 8]) = v;
  }
  __syncthreads();

  float sp[12];
#pragma unroll
  for (int i = 0; i < 12; i++) sp[i] = 0.f;

  for (int t = 0; t < 4; t++) {
    const int kk = k0 + t * 64 + wid * 16;
    f32x4 m[12] = {};
#pragma unroll 1
    for (int h = 0; h < 12; h++) {
      const _Float16* kp = Kh + ((size_t)(b * HH + h) * SS + kk + l15) * DD + g * 8;
      half8 kf0 = *reinterpret_cast<const half8*>(kp);
      half8 kf1 = *reinterpret_cast<const half8*>(kp + 32);
      half8 qa = *reinterpret_cast<const half8*>(&Qs[(h * 16 + l15) * 64 + (g ^ s7) * 8]);
      half8 qb =
          *reinterpret_cast<const half8*>(&Qs[(h * 16 + l15) * 64 + ((4 + g) ^ s7) * 8]);
      f32x4 a = {0.f, 0.f, 0.f, 0.f};
      a = __builtin_amdgcn_mfma_f32_16x16x32_f16(kf0, qa, a, 0, 0, 0);
      a = __builtin_amdgcn_mfma_f32_16x16x32_f16(kf1, qb, a, 0, 0, 0);
#pragma unroll
      for (int i = 0; i < 12; i++) m[i] += a * sW[h * 12 + i];
    }
#pragma unroll
    for (int i = 0; i < 12; i++)
      sp[i] += (__expf(m[i][0]) + __expf(m[i][1])) + (__expf(m[i][2]) + __expf(m[i][3]));
  }
#pragma unroll
  for (int i = 0; i < 12; i++) {
    float s = sp[i];
    s += __shfl_xor(s, 16);
    s += __shfl_xor(s, 32);
    if (lane < 16) sRed[wid][i][l15] = s;
  }
  __syncthreads();
  if (tid < 192) {
    int i = tid >> 4, q = tid & 15;
    float s = (sRed[0][i][q] + sRed[1][i][q]) + (sRed[2][i][q] + sRed[3][i][q]);
    atomicAdd(&S[(size_t)(b * HH + i) * SS + q0 + q], s);
  }
}

// ================= fused attention, pass 2: recompute + postmix + PV =================
// v4: k-split 2 (grid z) -> 1024 blocks (3/CU by LDS) + swizzled Qs/Ps (no pad,
// aligned b128, low bank conflict). Each z computes chunks z*8..z*8+7, stores f32
// partial O to Of[z]; combine_cvt sums halves -> Sc f16.
__global__ __launch_bounds__(256, 1) void attn_out(
    const _Float16* __restrict__ Qh, const _Float16* __restrict__ Kh,
    const _Float16* __restrict__ VTh, const float* __restrict__ S,
    const float* __restrict__ Wpre, const float* __restrict__ Wpost,
    float* __restrict__ Of) {
  __shared__ _Float16 Qs[12 * 16 * 64];
  __shared__ _Float16 Ps[12 * 16 * 64];
  __shared__ float sW[144];    // Wpre row-major [h][i]
  __shared__ float sW2t[144];  // Wpost^T [h][i]
  const int tid = threadIdx.x, lane = tid & 63, wid = tid >> 6;
  const int l15 = lane & 15, g = lane >> 4;
  const int s7 = l15 & 7;
  const int b = blockIdx.y, q0 = blockIdx.x * 16, z = blockIdx.z;
  const int h0 = wid * 3;

  for (int u = tid; u < 144; u += 256) {
    sW[u] = Wpre[u];
    sW2t[u] = Wpost[(u % 12) * 12 + (u / 12)];
  }
  for (int u = tid; u < 12 * 16 * 8; u += 256) {
    int h = u >> 7, q = (u >> 3) & 15, e8 = u & 7;
    half8 v = *reinterpret_cast<const half8*>(
        Qh + ((size_t)(b * HH + h) * SS + q0 + q) * DD + e8 * 8);
    *reinterpret_cast<half8*>(&Qs[(h * 16 + q) * 64 + (e8 ^ (q & 7)) * 8]) = v;
  }
  __syncthreads();

  float rs[12];
#pragma unroll
  for (int i = 0; i < 12; i++)
    rs[i] = 1.0f / S[(size_t)(b * HH + i) * SS + q0 + l15];

  f32x4 U[3][4] = {};  // [own-head][dtile]; q=(g*4+j), d=l15+dt*16

  for (int cc = 0; cc < 8; cc++) {
    const int c = z * 8 + cc;
    // ---- phase A: incremental premix ----
    const int kk = c * 64 + wid * 16;
    f32x4 m[12] = {};
#pragma unroll 1
    for (int h = 0; h < 12; h++) {
      const _Float16* kp = Kh + ((size_t)(b * HH + h) * SS + kk + l15) * DD + g * 8;
      half8 kf0 = *reinterpret_cast<const half8*>(kp);
      half8 kf1 = *reinterpret_cast<const half8*>(kp + 32);
      half8 qa = *reinterpret_cast<const half8*>(&Qs[(h * 16 + l15) * 64 + (g ^ s7) * 8]);
      half8 qb =
          *reinterpret_cast<const half8*>(&Qs[(h * 16 + l15) * 64 + ((4 + g) ^ s7) * 8]);
      f32x4 a = {0.f, 0.f, 0.f, 0.f};
      a = __builtin_amdgcn_mfma_f32_16x16x32_f16(kf0, qa, a, 0, 0, 0);
      a = __builtin_amdgcn_mfma_f32_16x16x32_f16(kf1, qb, a, 0, 0, 0);
#pragma unroll
      for (int i = 0; i < 12; i++) m[i] += a * sW[h * 12 + i];
    }
    // exp * 1/S in place
#pragma unroll
    for (int i = 0; i < 12; i++) {
      f32x4 e;
      e[0] = __expf(m[i][0]); e[1] = __expf(m[i][1]);
      e[2] = __expf(m[i][2]); e[3] = __expf(m[i][3]);
      m[i] = e * rs[i];
    }
    // postmix -> P tile in LDS (swizzled: row l15, elem (wid*16+g*4) block wid*2+(g>>1))
#pragma unroll
    for (int h = 0; h < 12; h++) {
      f32x4 p = m[0] * sW2t[h * 12];
#pragma unroll
      for (int i = 1; i < 12; i++) p += m[i] * sW2t[h * 12 + i];
      half4 p4;
      p4[0] = (_Float16)p[0]; p4[1] = (_Float16)p[1];
      p4[2] = (_Float16)p[2]; p4[3] = (_Float16)p[3];
      int o = ((wid * 2 + (g >> 1)) ^ s7) * 8 + (g & 1) * 4;
      *reinterpret_cast<half4*>(&Ps[(h * 16 + l15) * 64 + o]) = p4;
    }
    __syncthreads();
    // ---- phase B ----
#pragma unroll
    for (int kt = 0; kt < 4; kt++) {
#pragma unroll
      for (int ii = 0; ii < 3; ii++) {
        const int h = h0 + ii;
        int o = ((kt * 2 + (g >> 1)) ^ s7) * 8 + (g & 1) * 4;
        half4 af = *reinterpret_cast<const half4*>(&Ps[(h * 16 + l15) * 64 + o]);
        const _Float16* vp =
            VTh + ((size_t)(b * HH + h) * DD + l15) * SS + c * 64 + kt * 16 + g * 4;
#pragma unroll
        for (int dt = 0; dt < 4; dt++) {
          half4 bf = *reinterpret_cast<const half4*>(vp + (size_t)dt * 16 * SS);
          U[ii][dt] = __builtin_amdgcn_mfma_f32_16x16x16f16(af, bf, U[ii][dt], 0, 0, 0);
        }
      }
    }
    __syncthreads();
  }

  // store own heads: Of[z][b][q0+q][h*64+d] f32 (combined+converted later)
  float* ofp = Of + (size_t)z * NB * SS * CC;
#pragma unroll
  for (int ii = 0; ii < 3; ii++) {
    const int h = h0 + ii;
#pragma unroll
    for (int dt = 0; dt < 4; dt++)
#pragma unroll
      for (int j = 0; j < 4; j++)
        ofp[((size_t)b * SS + q0 + g * 4 + j) * CC + h * 64 + dt * 16 + l15] =
            U[ii][dt][j];
  }
}

extern "C" void kernel_launch(void* const* d_in, const int* in_sizes, int n_in,
                              void* d_out, int out_size, void* d_ws, size_t ws_size,
                              hipStream_t stream) {
  const float* inq = (const float*)d_in[0];
  const float* inkv = (const float*)d_in[1];
  const float* Wq = (const float*)d_in[2];
  const float* Wk = (const float*)d_in[3];
  const float* Wv = (const float*)d_in[4];
  const float* Wpre = (const float*)d_in[5];
  const float* Wpost = (const float*)d_in[6];
  const float* Wo = (const float*)d_in[7];
  float* out = (float*)d_out;

  const size_t nIn = (size_t)NB * SS * CC;
  const size_t nW = (size_t)CC * CC;
  const size_t nQ = (size_t)NB * HH * SS * DD;
  const size_t nSc = (size_t)NB * SS * CC;
  const size_t nS = (size_t)NB * HH * SS;  // f32 softmax sums

  char* ws = (char*)d_ws;
  size_t off = 0;
  auto take = [&](size_t elems) {
    _Float16* p = (_Float16*)(ws + off);
    off += elems * 2;
    return p;
  };
  _Float16* inqH = take(nIn);
  _Float16* inkvH = take(nIn);
  _Float16* WqT = take(nW);
  _Float16* WkT = take(nW);
  _Float16* WvT = take(nW);
  _Float16* WoT = take(nW);
  _Float16* Qh = take(nQ);
  _Float16* Kh = take(nQ);
  _Float16* VTh = take(nQ);
  _Float16* Sc = take(nSc);
  float* S = (float*)take(nS * 2);        // nS f32
  float* Of = (float*)take(nSc * 2 * 2);  // 2 x nSc f32 (k-split partials)

  dim3 blk(256);
  cvt_f16<<<dim3(2048), blk, 0, stream>>>(inq, inqH, (int)(nIn / 4));
  cvt_f16<<<dim3(2048), blk, 0, stream>>>(inkv, inkvH, (int)(nIn / 4));
  transp_f16<<<dim3(24, 24), blk, 0, stream>>>(Wq, WqT, CC, CC);
  transp_f16<<<dim3(24, 24), blk, 0, stream>>>(Wk, WkT, CC, CC);
  transp_f16<<<dim3(24, 24), blk, 0, stream>>>(Wv, WvT, CC, CC);
  transp_f16<<<dim3(24, 24), blk, 0, stream>>>(Wo, WoT, CC, CC);

  // projections
  gemm_bt<128, 128, 64, 1><<<dim3(CC / 128, NB * SS / 128), blk, 0, stream>>>(
      inqH, WqT, Qh, NB * SS, CC, CC, CC, CC, CC, 0.125f);
  gemm_bt<128, 128, 64, 1><<<dim3(CC / 128, NB * SS / 128), blk, 0, stream>>>(
      inkvH, WkT, Kh, NB * SS, CC, CC, CC, CC, CC, 1.0f);
  gemm_bt<128, 128, 64, 2><<<dim3(CC / 128, NB * SS / 128), blk, 0, stream>>>(
      inkvH, WvT, VTh, NB * SS, CC, CC, CC, CC, CC, 1.0f);

  // fused attention
  (void)hipMemsetAsync(S, 0, nS * sizeof(float), stream);
  attn_sums<<<dim3(4, 64, 8), blk, 0, stream>>>(Qh, Kh, Wpre, S);
  attn_out<<<dim3(64, 8, 2), blk, 0, stream>>>(Qh, Kh, VTh, S, Wpre, Wpost, Of);
  combine_cvt<<<dim3(2048), blk, 0, stream>>>(Of, Of + nSc, Sc, (int)(nSc / 4));

  // output projection -> f32 d_out
  gemm_bt<128, 128, 64, 3><<<dim3(CC / 128, NB * SS / 128), blk, 0, stream>>>(
      Sc, WoT, out, NB * SS, CC, CC, CC, CC, CC, 1.0f);
}

// Round 11
// 392.482 us; speedup vs baseline: 1.3994x; 1.3994x over previous
//
#include <hip/hip_runtime.h>

#define HH 12
#define SS 1024
#define CC 768
#define DD 64
#define NB 8

typedef _Float16 half8 __attribute__((ext_vector_type(8)));
typedef _Float16 half4 __attribute__((ext_vector_type(4)));
typedef float f32x4 __attribute__((ext_vector_type(4)));

// ---------------- f32 -> f16 convert (n4 = count/4) ----------------
__global__ __launch_bounds__(256) void cvt_f16(const float* __restrict__ src,
                                               _Float16* __restrict__ dst, int n4) {
  int i = blockIdx.x * 256 + threadIdx.x;
  int stride = gridDim.x * 256;
  for (; i < n4; i += stride) {
    f32x4 v = *reinterpret_cast<const f32x4*>(src + (size_t)i * 4);
    half4 o;
    o[0] = (_Float16)v[0]; o[1] = (_Float16)v[1];
    o[2] = (_Float16)v[2]; o[3] = (_Float16)v[3];
    *reinterpret_cast<half4*>(dst + (size_t)i * 4) = o;
  }
}

// ---------------- transpose RxC f32 -> CxR f16 ----------------
__global__ __launch_bounds__(256) void transp_f16(const float* __restrict__ src,
                                                  _Float16* __restrict__ dst, int R, int C) {
  __shared__ float tile[32][33];
  int tx = threadIdx.x & 31, ty = threadIdx.x >> 5;  // 32 x 8
  int r0 = blockIdx.y * 32, c0 = blockIdx.x * 32;
#pragma unroll
  for (int i = 0; i < 4; i++)
    tile[ty + i * 8][tx] = src[(size_t)(r0 + ty + i * 8) * C + c0 + tx];
  __syncthreads();
#pragma unroll
  for (int i = 0; i < 4; i++)
    dst[(size_t)(c0 + ty + i * 8) * R + r0 + tx] = (_Float16)tile[tx][ty + i * 8];
}

// ---------------- generic B-transposed GEMM ----------------
// CMODE: 1 = f16 QK layout [((b*12+h)*1024+s)*64+d]
//        2 = f16 V tiled layout [b][h][s/16][d/16][d&15][s&15]  (16x16 [d][s] tiles)
//        3 = f32 C at [row*ldc+col]
template <int BM, int BN, int BK, int CMODE>
__global__ __launch_bounds__(256) void gemm_bt(
    const _Float16* __restrict__ Abase, const _Float16* __restrict__ Bbase,
    void* __restrict__ Cbase, int M, int N, int K, int lda, int ldb, int ldc,
    float scale) {
  constexpr int WTM = BM / 2, WTN = BN / 2;
  constexpr int FM = WTM / 16, FN = WTN / 16;
  constexpr int AP = BM * BK / (256 * 8), BP = BN * BK / (256 * 8);
  __shared__ _Float16 sA[BM * BK];
  __shared__ _Float16 sB[BN * BK];
  const int tid = threadIdx.x;
  const int lane = tid & 63, wid = tid >> 6;
  const int wr = wid >> 1, wc = wid & 1;
  const int l15 = lane & 15, lhi = lane >> 4;
  const _Float16* A = Abase;
  const _Float16* B = Bbase;
  const int m0 = blockIdx.y * BM, n0 = blockIdx.x * BN;

  f32x4 acc[FM][FN] = {};
  const int nkt = K / BK;
  for (int kt = 0; kt < nkt; ++kt) {
    half8 ar[AP], br[BP];
#pragma unroll
    for (int p = 0; p < AP; p++) {
      int e = (p * 256 + tid) * 8;
      int r = e / BK, c = e % BK;
      ar[p] = *reinterpret_cast<const half8*>(A + (long)(m0 + r) * lda + kt * BK + c);
    }
#pragma unroll
    for (int p = 0; p < BP; p++) {
      int e = (p * 256 + tid) * 8;
      int r = e / BK, c = e % BK;
      br[p] = *reinterpret_cast<const half8*>(B + (long)(n0 + r) * ldb + kt * BK + c);
    }
    __syncthreads();
#pragma unroll
    for (int p = 0; p < AP; p++) {
      int e = (p * 256 + tid) * 8;
      *reinterpret_cast<half8*>(&sA[e]) = ar[p];
    }
#pragma unroll
    for (int p = 0; p < BP; p++) {
      int e = (p * 256 + tid) * 8;
      *reinterpret_cast<half8*>(&sB[e]) = br[p];
    }
    __syncthreads();
#pragma unroll
    for (int ks = 0; ks < BK / 32; ++ks) {
      half8 af[FM], bf[FN];
#pragma unroll
      for (int fm = 0; fm < FM; fm++)
        af[fm] = *reinterpret_cast<const half8*>(
            &sA[(wr * WTM + fm * 16 + l15) * BK + ks * 32 + lhi * 8]);
#pragma unroll
      for (int fn = 0; fn < FN; fn++)
        bf[fn] = *reinterpret_cast<const half8*>(
            &sB[(wc * WTN + fn * 16 + l15) * BK + ks * 32 + lhi * 8]);
#pragma unroll
      for (int fm = 0; fm < FM; fm++)
#pragma unroll
        for (int fn = 0; fn < FN; fn++)
          acc[fm][fn] =
              __builtin_amdgcn_mfma_f32_16x16x32_f16(af[fm], bf[fn], acc[fm][fn], 0, 0, 0);
    }
  }

#pragma unroll
  for (int fm = 0; fm < FM; fm++) {
#pragma unroll
    for (int fn = 0; fn < FN; fn++) {
#pragma unroll
      for (int j = 0; j < 4; j++) {
        int row = m0 + wr * WTM + fm * 16 + lhi * 4 + j;
        int col = n0 + wc * WTN + fn * 16 + l15;
        float v = acc[fm][fn][j] * scale;
        if constexpr (CMODE == 1) {
          int b = row >> 10, s = row & 1023, h = col >> 6, d = col & 63;
          reinterpret_cast<_Float16*>(Cbase)[((long)(b * HH + h) * SS + s) * DD + d] =
              (_Float16)v;
        } else if constexpr (CMODE == 2) {
          int b = row >> 10, s = row & 1023, h = col >> 6, d = col & 63;
          size_t idx = ((((size_t)(b * HH + h) * 64 + (s >> 4)) * 4 + (d >> 4)) << 8) +
                       ((d & 15) << 4) + (s & 15);
          reinterpret_cast<_Float16*>(Cbase)[idx] = (_Float16)v;
        } else {
          reinterpret_cast<float*>(Cbase)[(long)row * ldc + col] = v;
        }
      }
    }
  }
}

// ================= fused attention, pass 1: softmax denominators =================
// Grid (kchunk=4 x qtile=64 x b=8), 256 threads = 4 waves. Incremental premix.
__global__ __launch_bounds__(256, 1) void attn_sums(const _Float16* __restrict__ Qh,
                                                    const _Float16* __restrict__ Kh,
                                                    const float* __restrict__ Wpre,
                                                    float* __restrict__ S) {
  __shared__ _Float16 Qs[12 * 16 * 64];
  __shared__ float sW[144];  // Wpre row-major [h][i]
  __shared__ float sRed[4][12][16];
  const int tid = threadIdx.x, lane = tid & 63, wid = tid >> 6;
  const int l15 = lane & 15, g = lane >> 4;
  const int s7 = l15 & 7;
  const int b = blockIdx.z, q0 = blockIdx.y * 16, k0 = blockIdx.x * 256;

  for (int u = tid; u < 144; u += 256) sW[u] = Wpre[u];
  for (int u = tid; u < 12 * 16 * 8; u += 256) {
    int h = u >> 7, q = (u >> 3) & 15, e8 = u & 7;
    half8 v = *reinterpret_cast<const half8*>(
        Qh + ((size_t)(b * HH + h) * SS + q0 + q) * DD + e8 * 8);
    *reinterpret_cast<half8*>(&Qs[(h * 16 + q) * 64 + (e8 ^ (q & 7)) * 8]) = v;
  }
  __syncthreads();

  float sp[12];
#pragma unroll
  for (int i = 0; i < 12; i++) sp[i] = 0.f;

  for (int t = 0; t < 4; t++) {
    const int kk = k0 + t * 64 + wid * 16;
    f32x4 m[12] = {};
#pragma unroll 1
    for (int h = 0; h < 12; h++) {
      const _Float16* kp = Kh + ((size_t)(b * HH + h) * SS + kk + l15) * DD + g * 8;
      half8 kf0 = *reinterpret_cast<const half8*>(kp);
      half8 kf1 = *reinterpret_cast<const half8*>(kp + 32);
      half8 qa = *reinterpret_cast<const half8*>(&Qs[(h * 16 + l15) * 64 + (g ^ s7) * 8]);
      half8 qb =
          *reinterpret_cast<const half8*>(&Qs[(h * 16 + l15) * 64 + ((4 + g) ^ s7) * 8]);
      f32x4 a = {0.f, 0.f, 0.f, 0.f};
      a = __builtin_amdgcn_mfma_f32_16x16x32_f16(kf0, qa, a, 0, 0, 0);
      a = __builtin_amdgcn_mfma_f32_16x16x32_f16(kf1, qb, a, 0, 0, 0);
#pragma unroll
      for (int i = 0; i < 12; i++) m[i] += a * sW[h * 12 + i];
    }
#pragma unroll
    for (int i = 0; i < 12; i++)
      sp[i] += (__expf(m[i][0]) + __expf(m[i][1])) + (__expf(m[i][2]) + __expf(m[i][3]));
  }
#pragma unroll
  for (int i = 0; i < 12; i++) {
    float s = sp[i];
    s += __shfl_xor(s, 16);
    s += __shfl_xor(s, 32);
    if (lane < 16) sRed[wid][i][l15] = s;
  }
  __syncthreads();
  if (tid < 192) {
    int i = tid >> 4, q = tid & 15;
    float s = (sRed[0][i][q] + sRed[1][i][q]) + (sRed[2][i][q] + sRed[3][i][q]);
    atomicAdd(&S[(size_t)(b * HH + i) * SS + q0 + q], s);
  }
}

// ================= fused attention, pass 2: recompute + postmix + PV =================
// v5: V2 tiled [b][h][ktile][dtile][16d][16s] -> phase-B V loads are one contiguous
// 512B access per wave (was 16-way scattered 8B at 2KB stride = the R10 bottleneck).
// Grid (qtile=64, b=8), 4 waves, 16 chunks; direct f16 Sc store (k-split reverted).
__global__ __launch_bounds__(256, 1) void attn_out(
    const _Float16* __restrict__ Qh, const _Float16* __restrict__ Kh,
    const _Float16* __restrict__ V2, const float* __restrict__ S,
    const float* __restrict__ Wpre, const float* __restrict__ Wpost,
    _Float16* __restrict__ Sc) {
  __shared__ _Float16 Qs[12 * 16 * 64];
  __shared__ _Float16 Ps[12 * 16 * 64];
  __shared__ float sW[144];    // Wpre row-major [h][i]
  __shared__ float sW2t[144];  // Wpost^T [h][i]
  const int tid = threadIdx.x, lane = tid & 63, wid = tid >> 6;
  const int l15 = lane & 15, g = lane >> 4;
  const int s7 = l15 & 7;
  const int b = blockIdx.y, q0 = blockIdx.x * 16;
  const int h0 = wid * 3;

  for (int u = tid; u < 144; u += 256) {
    sW[u] = Wpre[u];
    sW2t[u] = Wpost[(u % 12) * 12 + (u / 12)];
  }
  for (int u = tid; u < 12 * 16 * 8; u += 256) {
    int h = u >> 7, q = (u >> 3) & 15, e8 = u & 7;
    half8 v = *reinterpret_cast<const half8*>(
        Qh + ((size_t)(b * HH + h) * SS + q0 + q) * DD + e8 * 8);
    *reinterpret_cast<half8*>(&Qs[(h * 16 + q) * 64 + (e8 ^ (q & 7)) * 8]) = v;
  }
  __syncthreads();

  float rs[12];
#pragma unroll
  for (int i = 0; i < 12; i++)
    rs[i] = 1.0f / S[(size_t)(b * HH + i) * SS + q0 + l15];

  f32x4 U[3][4] = {};  // [own-head][dtile]; q=(g*4+j), d=l15+dt*16

  for (int c = 0; c < 16; c++) {
    // ---- phase A: incremental premix ----
    const int kk = c * 64 + wid * 16;
    f32x4 m[12] = {};
#pragma unroll 1
    for (int h = 0; h < 12; h++) {
      const _Float16* kp = Kh + ((size_t)(b * HH + h) * SS + kk + l15) * DD + g * 8;
      half8 kf0 = *reinterpret_cast<const half8*>(kp);
      half8 kf1 = *reinterpret_cast<const half8*>(kp + 32);
      half8 qa = *reinterpret_cast<const half8*>(&Qs[(h * 16 + l15) * 64 + (g ^ s7) * 8]);
      half8 qb =
          *reinterpret_cast<const half8*>(&Qs[(h * 16 + l15) * 64 + ((4 + g) ^ s7) * 8]);
      f32x4 a = {0.f, 0.f, 0.f, 0.f};
      a = __builtin_amdgcn_mfma_f32_16x16x32_f16(kf0, qa, a, 0, 0, 0);
      a = __builtin_amdgcn_mfma_f32_16x16x32_f16(kf1, qb, a, 0, 0, 0);
#pragma unroll
      for (int i = 0; i < 12; i++) m[i] += a * sW[h * 12 + i];
    }
    // exp * 1/S in place
#pragma unroll
    for (int i = 0; i < 12; i++) {
      f32x4 e;
      e[0] = __expf(m[i][0]); e[1] = __expf(m[i][1]);
      e[2] = __expf(m[i][2]); e[3] = __expf(m[i][3]);
      m[i] = e * rs[i];
    }
    // postmix -> P tile in LDS (swizzled)
#pragma unroll
    for (int h = 0; h < 12; h++) {
      f32x4 p = m[0] * sW2t[h * 12];
#pragma unroll
      for (int i = 1; i < 12; i++) p += m[i] * sW2t[h * 12 + i];
      half4 p4;
      p4[0] = (_Float16)p[0]; p4[1] = (_Float16)p[1];
      p4[2] = (_Float16)p[2]; p4[3] = (_Float16)p[3];
      int o = ((wid * 2 + (g >> 1)) ^ s7) * 8 + (g & 1) * 4;
      *reinterpret_cast<half4*>(&Ps[(h * 16 + l15) * 64 + o]) = p4;
    }
    __syncthreads();
    // ---- phase B: P (LDS) x V2 tiles (coalesced) ----
#pragma unroll
    for (int kt = 0; kt < 4; kt++) {
#pragma unroll
      for (int ii = 0; ii < 3; ii++) {
        const int h = h0 + ii;
        int o = ((kt * 2 + (g >> 1)) ^ s7) * 8 + (g & 1) * 4;
        half4 af = *reinterpret_cast<const half4*>(&Ps[(h * 16 + l15) * 64 + o]);
        const _Float16* vp =
            V2 + ((((size_t)(b * HH + h) * 64 + (c * 4 + kt)) * 4) << 8) + l15 * 16 + g * 4;
#pragma unroll
        for (int dt = 0; dt < 4; dt++) {
          half4 bf = *reinterpret_cast<const half4*>(vp + (dt << 8));
          U[ii][dt] = __builtin_amdgcn_mfma_f32_16x16x16f16(af, bf, U[ii][dt], 0, 0, 0);
        }
      }
    }
    __syncthreads();
  }

  // store own heads: Sc[b][q0+q][h*64+d] f16
#pragma unroll
  for (int ii = 0; ii < 3; ii++) {
    const int h = h0 + ii;
#pragma unroll
    for (int dt = 0; dt < 4; dt++)
#pragma unroll
      for (int j = 0; j < 4; j++)
        Sc[((size_t)b * SS + q0 + g * 4 + j) * CC + h * 64 + dt * 16 + l15] =
            (_Float16)U[ii][dt][j];
  }
}

extern "C" void kernel_launch(void* const* d_in, const int* in_sizes, int n_in,
                              void* d_out, int out_size, void* d_ws, size_t ws_size,
                              hipStream_t stream) {
  const float* inq = (const float*)d_in[0];
  const float* inkv = (const float*)d_in[1];
  const float* Wq = (const float*)d_in[2];
  const float* Wk = (const float*)d_in[3];
  const float* Wv = (const float*)d_in[4];
  const float* Wpre = (const float*)d_in[5];
  const float* Wpost = (const float*)d_in[6];
  const float* Wo = (const float*)d_in[7];
  float* out = (float*)d_out;

  const size_t nIn = (size_t)NB * SS * CC;
  const size_t nW = (size_t)CC * CC;
  const size_t nQ = (size_t)NB * HH * SS * DD;
  const size_t nSc = (size_t)NB * SS * CC;
  const size_t nS = (size_t)NB * HH * SS;  // f32 softmax sums

  char* ws = (char*)d_ws;
  size_t off = 0;
  auto take = [&](size_t elems) {
    _Float16* p = (_Float16*)(ws + off);
    off += elems * 2;
    return p;
  };
  _Float16* inqH = take(nIn);
  _Float16* inkvH = take(nIn);
  _Float16* WqT = take(nW);
  _Float16* WkT = take(nW);
  _Float16* WvT = take(nW);
  _Float16* WoT = take(nW);
  _Float16* Qh = take(nQ);
  _Float16* Kh = take(nQ);
  _Float16* V2 = take(nQ);
  _Float16* Sc = take(nSc);
  float* S = (float*)take(nS * 2);  // nS f32

  dim3 blk(256);
  cvt_f16<<<dim3(2048), blk, 0, stream>>>(inq, inqH, (int)(nIn / 4));
  cvt_f16<<<dim3(2048), blk, 0, stream>>>(inkv, inkvH, (int)(nIn / 4));
  transp_f16<<<dim3(24, 24), blk, 0, stream>>>(Wq, WqT, CC, CC);
  transp_f16<<<dim3(24, 24), blk, 0, stream>>>(Wk, WkT, CC, CC);
  transp_f16<<<dim3(24, 24), blk, 0, stream>>>(Wv, WvT, CC, CC);
  transp_f16<<<dim3(24, 24), blk, 0, stream>>>(Wo, WoT, CC, CC);

  // projections
  gemm_bt<128, 128, 64, 1><<<dim3(CC / 128, NB * SS / 128), blk, 0, stream>>>(
      inqH, WqT, Qh, NB * SS, CC, CC, CC, CC, CC, 0.125f);
  gemm_bt<128, 128, 64, 1><<<dim3(CC / 128, NB * SS / 128), blk, 0, stream>>>(
      inkvH, WkT, Kh, NB * SS, CC, CC, CC, CC, CC, 1.0f);
  gemm_bt<128, 128, 64, 2><<<dim3(CC / 128, NB * SS / 128), blk, 0, stream>>>(
      inkvH, WvT, V2, NB * SS, CC, CC, CC, CC, CC, 1.0f);

  // fused attention
  (void)hipMemsetAsync(S, 0, nS * sizeof(float), stream);
  attn_sums<<<dim3(4, 64, 8), blk, 0, stream>>>(Qh, Kh, Wpre, S);
  attn_out<<<dim3(64, 8), blk, 0, stream>>>(Qh, Kh, V2, S, Wpre, Wpost, Sc);

  // output projection -> f32 d_out
  gemm_bt<128, 128, 64, 3><<<dim3(CC / 128, NB * SS / 128), blk, 0, stream>>>(
      Sc, WoT, out, NB * SS, CC, CC, CC, CC, CC, 1.0f);
}